// Round 1
// baseline (466.643 us; speedup 1.0000x reference)
//
#include <hip/hip_runtime.h>

// ---------------------------------------------------------------------------
// Types / helpers
// ---------------------------------------------------------------------------
typedef __bf16 bf16x8 __attribute__((ext_vector_type(8)));
typedef float  f32x4  __attribute__((ext_vector_type(4)));

union U8 { bf16x8 v; __bf16 e[8]; unsigned short u[8]; };

__device__ __forceinline__ unsigned short f2bf(float f) {
  unsigned int u = __float_as_uint(f);
  unsigned int r = (u + 0x7FFFu + ((u >> 16) & 1u)) >> 16;  // RNE
  return (unsigned short)r;
}

__device__ __forceinline__ void async16(const void* g, void* l) {
  __builtin_amdgcn_global_load_lds(
      (__attribute__((address_space(1))) void*)(g),
      (__attribute__((address_space(3))) void*)(l), 16, 0, 0);
}

// ---------------------------------------------------------------------------
// Batched transpose: in fp32 [batch][R][Cc] -> out bf16 [batch*Cc + c][R]
// (i.e. weights stored as B^T [N][K] for the GEMM). R, Cc multiples of 32.
// ---------------------------------------------------------------------------
__global__ __launch_bounds__(256) void transpose_w(
    const float* __restrict__ in, unsigned short* __restrict__ out,
    int R, int Cc) {
  __shared__ float tile[32][33];
  const int batch = blockIdx.z;
  const float* ip = in + (size_t)batch * R * Cc;
  unsigned short* op = out + (size_t)batch * R * Cc;
  const int c0 = blockIdx.x * 32, r0 = blockIdx.y * 32;
  const int tx = threadIdx.x, ty = threadIdx.y;  // 32 x 8
#pragma unroll
  for (int i = 0; i < 32; i += 8)
    tile[ty + i][tx] = ip[(size_t)(r0 + ty + i) * Cc + c0 + tx];
  __syncthreads();
#pragma unroll
  for (int i = 0; i < 32; i += 8)
    op[(size_t)(c0 + ty + i) * R + r0 + tx] = f2bf(tile[tx][ty + i]);
}

// ---------------------------------------------------------------------------
// LayerNorm over rows of 1024, fp32 in -> bf16 out. 256 thr, 4 elems/thr.
// ---------------------------------------------------------------------------
__global__ __launch_bounds__(256) void ln_kernel(
    const float* __restrict__ x, const float* __restrict__ g,
    const float* __restrict__ bta, unsigned short* __restrict__ out) {
  const int C = 1024;
  const int row = blockIdx.x, tid = threadIdx.x;
  const float4 v = ((const float4*)(x + (size_t)row * C))[tid];
  float s  = v.x + v.y + v.z + v.w;
  float ss = v.x * v.x + v.y * v.y + v.z * v.z + v.w * v.w;
#pragma unroll
  for (int off = 32; off > 0; off >>= 1) {
    s  += __shfl_down(s, off);
    ss += __shfl_down(ss, off);
  }
  __shared__ float r0[4], r1[4];
  const int wave = tid >> 6, lane = tid & 63;
  if (lane == 0) { r0[wave] = s; r1[wave] = ss; }
  __syncthreads();
  s  = r0[0] + r0[1] + r0[2] + r0[3];
  ss = r1[0] + r1[1] + r1[2] + r1[3];
  const float mu   = s * (1.0f / C);
  const float var  = ss * (1.0f / C) - mu * mu;
  const float rstd = rsqrtf(var + 1e-5f);
  const float4 gv = ((const float4*)g)[tid];
  const float4 bv = ((const float4*)bta)[tid];
  ushort4 o;
  o.x = f2bf((v.x - mu) * rstd * gv.x + bv.x);
  o.y = f2bf((v.y - mu) * rstd * gv.y + bv.y);
  o.z = f2bf((v.z - mu) * rstd * gv.z + bv.z);
  o.w = f2bf((v.w - mu) * rstd * gv.w + bv.w);
  ((ushort4*)(out + (size_t)row * C))[tid] = o;
}

// ---------------------------------------------------------------------------
// GEMM: C[M][N] = A[M][K] * B, with B given transposed BT[N][K]. bf16 in,
// fp32 accum. m97 structure: 128x128 tile, BK=32, 4 waves of 64x64,
// global_load_lds(16B) staging, ds_read_b128 frags, mfma 16x16x32 bf16.
// EPI: 0 = store bf16; 1 = +bias+resid -> fp32; 2 = relu(+bias) -> bf16;
//      3 = +bias+resid -> fp32
// ---------------------------------------------------------------------------
template <int EPI>
__global__ __launch_bounds__(256, 2) void gemm_bt(
    const unsigned short* __restrict__ A, const unsigned short* __restrict__ BT,
    void* __restrict__ Cout, const float* __restrict__ bias,
    const float* __restrict__ resid, int M, int N, int K) {
  __shared__ __align__(16) unsigned short As[128 * 32];
  __shared__ __align__(16) unsigned short Bs[128 * 32];
  const int tid = threadIdx.x;
  const int lane = tid & 63, wave = tid >> 6;
  const int wrow = wave >> 1, wcol = wave & 1;
  const int lr = lane & 15, lg = lane >> 4;
  const int m0 = blockIdx.y * 128, n0 = blockIdx.x * 128;

  f32x4 acc[4][4] = {};

  const int srow = tid >> 2, k8 = (tid & 3) << 3;
  const size_t arow0 = (size_t)(m0 + srow) * K + k8;
  const size_t brow0 = (size_t)(n0 + srow) * K + k8;
  const size_t skip64 = (size_t)64 * K;

  for (int kt = 0; kt < K; kt += 32) {
    async16(A + arow0 + kt, As + tid * 8);
    async16(A + arow0 + skip64 + kt, As + tid * 8 + 2048);
    async16(BT + brow0 + kt, Bs + tid * 8);
    async16(BT + brow0 + skip64 + kt, Bs + tid * 8 + 2048);
    __syncthreads();
    bf16x8 af[4], bfr[4];
#pragma unroll
    for (int i = 0; i < 4; i++)
      af[i] = *(const bf16x8*)(As + (wrow * 64 + i * 16 + lr) * 32 + lg * 8);
#pragma unroll
    for (int j = 0; j < 4; j++)
      bfr[j] = *(const bf16x8*)(Bs + (wcol * 64 + j * 16 + lr) * 32 + lg * 8);
#pragma unroll
    for (int i = 0; i < 4; i++)
#pragma unroll
      for (int j = 0; j < 4; j++)
        acc[i][j] =
            __builtin_amdgcn_mfma_f32_16x16x32_bf16(af[i], bfr[j], acc[i][j], 0, 0, 0);
    __syncthreads();
  }

#pragma unroll
  for (int j = 0; j < 4; j++) {
    const int col = n0 + wcol * 64 + j * 16 + lr;
    float bv = 0.0f;
    if (EPI != 0) bv = bias[col];
#pragma unroll
    for (int i = 0; i < 4; i++) {
#pragma unroll
      for (int r = 0; r < 4; r++) {
        const int rrow = m0 + wrow * 64 + i * 16 + lg * 4 + r;
        const size_t idx = (size_t)rrow * N + col;
        const float val = acc[i][j][r];
        if (EPI == 0) {
          ((unsigned short*)Cout)[idx] = f2bf(val);
        } else if (EPI == 1) {
          ((float*)Cout)[idx] = val + bv + resid[idx];
        } else if (EPI == 2) {
          ((unsigned short*)Cout)[idx] = f2bf(fmaxf(val + bv, 0.0f));
        } else {
          ((float*)Cout)[idx] = val + bv + resid[idx];
        }
      }
    }
  }
}

// ---------------------------------------------------------------------------
// Flash attention (causal). q,k,v,o: bf16 [B][T][H*64] (head-blocked cols).
// Block = 4 waves; each wave owns 16 Q rows of one (b,h). s-blocks of 32.
// ---------------------------------------------------------------------------
__global__ __launch_bounds__(256) void attn_kernel(
    const unsigned short* __restrict__ q, const unsigned short* __restrict__ k,
    const unsigned short* __restrict__ v, unsigned short* __restrict__ o) {
  const int T = 2048, C = 1024;
  const int wave = threadIdx.x >> 6, lane = threadIdx.x & 63;
  const int lr = lane & 15, lg = lane >> 4;
  const int qbase = blockIdx.x * 64 + wave * 16;
  const int b = blockIdx.y >> 4, hh = blockIdx.y & 15;
  const size_t base = ((size_t)b * T) * C + hh * 64;

  __shared__ __align__(16) unsigned short p_lds[4][16][32];

  U8 qf[2];
#pragma unroll
  for (int j = 0; j < 2; j++)
    qf[j].v = *(const bf16x8*)(q + base + (size_t)(qbase + lr) * C + j * 32 + lg * 8);

  f32x4 oa[4] = {};
  float m[4], lsum[4];
#pragma unroll
  for (int r = 0; r < 4; r++) { m[r] = -1e30f; lsum[r] = 0.0f; }

  const int nsb = (qbase + 15) >> 5;
  for (int sb = 0; sb <= nsb; sb++) {
    const int s0 = sb * 32;
    f32x4 sa0 = {}, sa1 = {};
#pragma unroll
    for (int j = 0; j < 2; j++) {
      U8 kf0, kf1;
      kf0.v = *(const bf16x8*)(k + base + (size_t)(s0 + lr) * C + j * 32 + lg * 8);
      kf1.v = *(const bf16x8*)(k + base + (size_t)(s0 + 16 + lr) * C + j * 32 + lg * 8);
      sa0 = __builtin_amdgcn_mfma_f32_16x16x32_bf16(qf[j].v, kf0.v, sa0, 0, 0, 0);
      sa1 = __builtin_amdgcn_mfma_f32_16x16x32_bf16(qf[j].v, kf1.v, sa1, 0, 0, 0);
    }
    float sv[8];
#pragma unroll
    for (int r = 0; r < 4; r++) {
      sv[r]     = sa0[r] * 0.125f;
      sv[4 + r] = sa1[r] * 0.125f;
    }
    if (s0 + 31 > qbase) {  // diagonal block: apply causal mask
#pragma unroll
      for (int r = 0; r < 4; r++) {
        const int t = qbase + lg * 4 + r;
        if (s0 + lr > t)      sv[r]     = -1e30f;
        if (s0 + 16 + lr > t) sv[4 + r] = -1e30f;
      }
    }
    float tm[4];
#pragma unroll
    for (int r = 0; r < 4; r++) tm[r] = fmaxf(sv[r], sv[4 + r]);
#pragma unroll
    for (int d = 1; d < 16; d <<= 1) {
#pragma unroll
      for (int r = 0; r < 4; r++) tm[r] = fmaxf(tm[r], __shfl_xor(tm[r], d));
    }
    float mn[4], corr[4], rs[4];
#pragma unroll
    for (int r = 0; r < 4; r++) {
      mn[r]   = fmaxf(m[r], tm[r]);
      corr[r] = __expf(m[r] - mn[r]);
      sv[r]     = __expf(sv[r] - mn[r]);
      sv[4 + r] = __expf(sv[4 + r] - mn[r]);
      rs[r] = sv[r] + sv[4 + r];
    }
#pragma unroll
    for (int d = 1; d < 16; d <<= 1) {
#pragma unroll
      for (int r = 0; r < 4; r++) rs[r] += __shfl_xor(rs[r], d);
    }
#pragma unroll
    for (int r = 0; r < 4; r++) {
      lsum[r] = lsum[r] * corr[r] + rs[r];
      m[r] = mn[r];
    }
#pragma unroll
    for (int c = 0; c < 4; c++)
#pragma unroll
      for (int r = 0; r < 4; r++) oa[c][r] *= corr[r];

    // P (scores) -> LDS, re-read in A-frag layout (intra-wave transpose)
#pragma unroll
    for (int r = 0; r < 4; r++) {
      p_lds[wave][lg * 4 + r][lr]      = f2bf(sv[r]);
      p_lds[wave][lg * 4 + r][16 + lr] = f2bf(sv[4 + r]);
    }
    asm volatile("" ::: "memory");
    U8 pf;
    pf.v = *(const bf16x8*)(&p_lds[wave][lr][lg * 8]);
    asm volatile("" ::: "memory");

#pragma unroll
    for (int c = 0; c < 4; c++) {
      U8 vf;
#pragma unroll
      for (int i = 0; i < 8; i++)
        vf.u[i] = v[base + (size_t)(s0 + lg * 8 + i) * C + c * 16 + lr];
      oa[c] = __builtin_amdgcn_mfma_f32_16x16x32_bf16(pf.v, vf.v, oa[c], 0, 0, 0);
    }
  }

#pragma unroll
  for (int c = 0; c < 4; c++)
#pragma unroll
    for (int r = 0; r < 4; r++) {
      const int t = qbase + lg * 4 + r;
      o[base + (size_t)t * C + c * 16 + lr] = f2bf(oa[c][r] / lsum[r]);
    }
}

// ---------------------------------------------------------------------------
// Orchestration
// ---------------------------------------------------------------------------
extern "C" void kernel_launch(void* const* d_in, const int* in_sizes, int n_in,
                              void* d_out, int out_size, void* d_ws, size_t ws_size,
                              hipStream_t stream) {
  (void)in_sizes; (void)n_in; (void)out_size; (void)ws_size;
  const int T = 2048, C = 1024, M = 2 * T /*B*T*/, C4 = 4 * C;

  const float* x     = (const float*)d_in[0];
  const float* Wq    = (const float*)d_in[1];
  const float* Wk    = (const float*)d_in[2];
  const float* Wv    = (const float*)d_in[3];
  const float* Wproj = (const float*)d_in[4];
  const float* bproj = (const float*)d_in[5];
  const float* W1    = (const float*)d_in[6];
  const float* b1    = (const float*)d_in[7];
  const float* W2    = (const float*)d_in[8];
  const float* b2    = (const float*)d_in[9];
  const float* ln1g  = (const float*)d_in[10];
  const float* ln1b  = (const float*)d_in[11];
  const float* ln2g  = (const float*)d_in[12];
  const float* ln2b  = (const float*)d_in[13];
  float* out = (float*)d_out;

  // Workspace layout (80 MB total, with lifetime-based reuse):
  char* ws = (char*)d_ws;
  const size_t MBy = (size_t)1 << 20;
  unsigned short* WqT = (unsigned short*)(ws + 0 * MBy);    // 2 MB  [1024][1024]
  unsigned short* WkT = (unsigned short*)(ws + 2 * MBy);    // 2 MB
  unsigned short* WvT = (unsigned short*)(ws + 4 * MBy);    // 2 MB
  unsigned short* WpT = (unsigned short*)(ws + 6 * MBy);    // 2 MB
  unsigned short* W1T = (unsigned short*)(ws + 8 * MBy);    // 8 MB  [4096][1024]
  unsigned short* W2T = (unsigned short*)(ws + 16 * MBy);   // 8 MB  [1024][4096]
  unsigned short* h   = (unsigned short*)(ws + 24 * MBy);   // 8 MB
  unsigned short* qb  = (unsigned short*)(ws + 32 * MBy);   // 8 MB
  unsigned short* kb  = (unsigned short*)(ws + 40 * MBy);   // 8 MB
  unsigned short* vb  = (unsigned short*)(ws + 48 * MBy);   // 8 MB
  unsigned short* att = (unsigned short*)(ws + 56 * MBy);   // 8 MB
  float*          x1  = (float*)(ws + 64 * MBy);            // 16 MB
  unsigned short* h2  = (unsigned short*)(ws + 56 * MBy);   // reuse att slot (dead after proj)
  unsigned short* ff1 = (unsigned short*)(ws + 24 * MBy);   // 32 MB, reuse h/q/k/v (dead after attn)

  const dim3 tb(32, 8);
  transpose_w<<<dim3(2, 32, 16), tb, 0, stream>>>(Wq, WqT, 1024, 64);
  transpose_w<<<dim3(2, 32, 16), tb, 0, stream>>>(Wk, WkT, 1024, 64);
  transpose_w<<<dim3(2, 32, 16), tb, 0, stream>>>(Wv, WvT, 1024, 64);
  transpose_w<<<dim3(32, 32, 1), tb, 0, stream>>>(Wproj, WpT, 1024, 1024);
  transpose_w<<<dim3(128, 32, 1), tb, 0, stream>>>(W1, W1T, 1024, 4096);
  transpose_w<<<dim3(32, 128, 1), tb, 0, stream>>>(W2, W2T, 4096, 1024);

  ln_kernel<<<M, 256, 0, stream>>>(x, ln1g, ln1b, h);

  gemm_bt<0><<<dim3(8, 32), 256, 0, stream>>>(h, WqT, qb, nullptr, nullptr, M, C, C);
  gemm_bt<0><<<dim3(8, 32), 256, 0, stream>>>(h, WkT, kb, nullptr, nullptr, M, C, C);
  gemm_bt<0><<<dim3(8, 32), 256, 0, stream>>>(h, WvT, vb, nullptr, nullptr, M, C, C);

  attn_kernel<<<dim3(32, 32), 256, 0, stream>>>(qb, kb, vb, att);

  gemm_bt<1><<<dim3(8, 32), 256, 0, stream>>>(att, WpT, x1, bproj, x, M, C, C);

  ln_kernel<<<M, 256, 0, stream>>>(x1, ln2g, ln2b, h2);

  gemm_bt<2><<<dim3(32, 32), 256, 0, stream>>>(h2, W1T, ff1, b1, nullptr, M, C4, C);
  gemm_bt<3><<<dim3(8, 32), 256, 0, stream>>>(ff1, W2T, out, b2, x1, M, C, C4);
}

// Round 2
// 348.497 us; speedup vs baseline: 1.3390x; 1.3390x over previous
//
#include <hip/hip_runtime.h>

// ---------------------------------------------------------------------------
// Types / helpers
// ---------------------------------------------------------------------------
typedef __bf16 bf16x8 __attribute__((ext_vector_type(8)));
typedef float  f32x4  __attribute__((ext_vector_type(4)));

union U8 { bf16x8 v; __bf16 e[8]; unsigned short u[8]; };

__device__ __forceinline__ unsigned short f2bf(float f) {
  unsigned int u = __float_as_uint(f);
  unsigned int r = (u + 0x7FFFu + ((u >> 16) & 1u)) >> 16;  // RNE
  return (unsigned short)r;
}

__device__ __forceinline__ void async16(const void* g, void* l) {
  __builtin_amdgcn_global_load_lds(
      (__attribute__((address_space(1))) void*)(g),
      (__attribute__((address_space(3))) void*)(l), 16, 0, 0);
}

// ---------------------------------------------------------------------------
// Batched transpose: in fp32 [batch][R][Cc] -> out bf16 [batch*Cc + c][R]
// ---------------------------------------------------------------------------
__global__ __launch_bounds__(256) void transpose_w(
    const float* __restrict__ in, unsigned short* __restrict__ out,
    int R, int Cc) {
  __shared__ float tile[32][33];
  const int batch = blockIdx.z;
  const float* ip = in + (size_t)batch * R * Cc;
  unsigned short* op = out + (size_t)batch * R * Cc;
  const int c0 = blockIdx.x * 32, r0 = blockIdx.y * 32;
  const int tx = threadIdx.x, ty = threadIdx.y;  // 32 x 8
#pragma unroll
  for (int i = 0; i < 32; i += 8)
    tile[ty + i][tx] = ip[(size_t)(r0 + ty + i) * Cc + c0 + tx];
  __syncthreads();
#pragma unroll
  for (int i = 0; i < 32; i += 8)
    op[(size_t)(c0 + ty + i) * R + r0 + tx] = f2bf(tile[tx][ty + i]);
}

// ---------------------------------------------------------------------------
// LayerNorm over rows of 1024, fp32 in -> bf16 out.
// ---------------------------------------------------------------------------
__global__ __launch_bounds__(256) void ln_kernel(
    const float* __restrict__ x, const float* __restrict__ g,
    const float* __restrict__ bta, unsigned short* __restrict__ out) {
  const int C = 1024;
  const int row = blockIdx.x, tid = threadIdx.x;
  const float4 v = ((const float4*)(x + (size_t)row * C))[tid];
  float s  = v.x + v.y + v.z + v.w;
  float ss = v.x * v.x + v.y * v.y + v.z * v.z + v.w * v.w;
#pragma unroll
  for (int off = 32; off > 0; off >>= 1) {
    s  += __shfl_down(s, off);
    ss += __shfl_down(ss, off);
  }
  __shared__ float r0[4], r1[4];
  const int wave = tid >> 6, lane = tid & 63;
  if (lane == 0) { r0[wave] = s; r1[wave] = ss; }
  __syncthreads();
  s  = r0[0] + r0[1] + r0[2] + r0[3];
  ss = r1[0] + r1[1] + r1[2] + r1[3];
  const float mu   = s * (1.0f / C);
  const float var  = ss * (1.0f / C) - mu * mu;
  const float rstd = rsqrtf(var + 1e-5f);
  const float4 gv = ((const float4*)g)[tid];
  const float4 bv = ((const float4*)bta)[tid];
  ushort4 o;
  o.x = f2bf((v.x - mu) * rstd * gv.x + bv.x);
  o.y = f2bf((v.y - mu) * rstd * gv.y + bv.y);
  o.z = f2bf((v.z - mu) * rstd * gv.z + bv.z);
  o.w = f2bf((v.w - mu) * rstd * gv.w + bv.w);
  ((ushort4*)(out + (size_t)row * C))[tid] = o;
}

// ---------------------------------------------------------------------------
// GEMM: C[M][N] = A[M][K] * BT[N][K]^T. bf16 in, fp32 accum. m97 structure.
// EPI: 0 = store bf16 [M][N]
//      1 = +bias+resid -> fp32
//      2 = relu(+bias) -> bf16
//      3 = +bias+resid -> fp32
//      4 = QKV split: col<2048 -> bf16 Cout[M][2048]; col>=2048 ->
//          transposed bf16 Cout2[(col-2048)][M] (ushort4 over 4 rows)
// ---------------------------------------------------------------------------
template <int EPI>
__global__ __launch_bounds__(256, 2) void gemm_bt(
    const unsigned short* __restrict__ A, const unsigned short* __restrict__ BT,
    void* __restrict__ Cout, void* __restrict__ Cout2,
    const float* __restrict__ bias, const float* __restrict__ resid,
    int M, int N, int K) {
  __shared__ __align__(16) unsigned short As[128 * 32];
  __shared__ __align__(16) unsigned short Bs[128 * 32];
  const int tid = threadIdx.x;
  const int lane = tid & 63, wave = tid >> 6;
  const int wrow = wave >> 1, wcol = wave & 1;
  const int lr = lane & 15, lg = lane >> 4;
  const int m0 = blockIdx.y * 128, n0 = blockIdx.x * 128;

  f32x4 acc[4][4] = {};

  const int srow = tid >> 2, k8 = (tid & 3) << 3;
  const size_t arow0 = (size_t)(m0 + srow) * K + k8;
  const size_t brow0 = (size_t)(n0 + srow) * K + k8;
  const size_t skip64 = (size_t)64 * K;

  for (int kt = 0; kt < K; kt += 32) {
    async16(A + arow0 + kt, As + tid * 8);
    async16(A + arow0 + skip64 + kt, As + tid * 8 + 2048);
    async16(BT + brow0 + kt, Bs + tid * 8);
    async16(BT + brow0 + skip64 + kt, Bs + tid * 8 + 2048);
    __syncthreads();
    bf16x8 af[4], bfr[4];
#pragma unroll
    for (int i = 0; i < 4; i++)
      af[i] = *(const bf16x8*)(As + (wrow * 64 + i * 16 + lr) * 32 + lg * 8);
#pragma unroll
    for (int j = 0; j < 4; j++)
      bfr[j] = *(const bf16x8*)(Bs + (wcol * 64 + j * 16 + lr) * 32 + lg * 8);
#pragma unroll
    for (int i = 0; i < 4; i++)
#pragma unroll
      for (int j = 0; j < 4; j++)
        acc[i][j] =
            __builtin_amdgcn_mfma_f32_16x16x32_bf16(af[i], bfr[j], acc[i][j], 0, 0, 0);
    __syncthreads();
  }

#pragma unroll
  for (int j = 0; j < 4; j++) {
    const int col = n0 + wcol * 64 + j * 16 + lr;
    float bv = 0.0f;
    if (EPI == 1 || EPI == 2 || EPI == 3) bv = bias[col];
#pragma unroll
    for (int i = 0; i < 4; i++) {
      const int row0 = m0 + wrow * 64 + i * 16 + lg * 4;
      if (EPI == 4) {
        if (col < 2048) {
#pragma unroll
          for (int r = 0; r < 4; r++)
            ((unsigned short*)Cout)[(size_t)(row0 + r) * 2048 + col] =
                f2bf(acc[i][j][r]);
        } else {
          ushort4 ov;
          ov.x = f2bf(acc[i][j][0]);
          ov.y = f2bf(acc[i][j][1]);
          ov.z = f2bf(acc[i][j][2]);
          ov.w = f2bf(acc[i][j][3]);
          *(ushort4*)((unsigned short*)Cout2 + (size_t)(col - 2048) * 4096 + row0) = ov;
        }
      } else {
#pragma unroll
        for (int r = 0; r < 4; r++) {
          const size_t idx = (size_t)(row0 + r) * N + col;
          const float val = acc[i][j][r];
          if (EPI == 0) {
            ((unsigned short*)Cout)[idx] = f2bf(val);
          } else if (EPI == 1) {
            ((float*)Cout)[idx] = val + bv + resid[idx];
          } else if (EPI == 2) {
            ((unsigned short*)Cout)[idx] = f2bf(fmaxf(val + bv, 0.0f));
          } else {
            ((float*)Cout)[idx] = val + bv + resid[idx];
          }
        }
      }
    }
  }
}

// ---------------------------------------------------------------------------
// Flash attention (causal), swapped-operand form.
// qk: bf16 [B*T][2048] (cols 0..1023 = Q heads, 1024..2047 = K heads)
// vT: bf16 [1024][B*T]  (vT[h*64+d][b*2048+s])
// o : bf16 [B*T][1024]
// Swapped QK:  S^T = mfma(Kfrag, Qfrag)  -> lane (lr,lg) holds S[m=lr][s=lg*4+r]
// Swapped PV:  O^T = mfma(Vfrag, Pfrag)  -> lane (lr,lg) holds O[m=lr][d=c*16+lg*4+r]
// Softmax fully lane-local per q-row; cross-lane only 2 shfl_xor (16,32) pairs.
// Causal load-balance: block bx processes q-tiles {bx, 31-bx}.
// ---------------------------------------------------------------------------
__global__ __launch_bounds__(256) void attn_kernel(
    const unsigned short* __restrict__ qk, const unsigned short* __restrict__ vT,
    unsigned short* __restrict__ o) {
  const int T = 2048, C = 1024, QKS = 2048;
  const int wave = threadIdx.x >> 6, lane = threadIdx.x & 63;
  const int lr = lane & 15, lg = lane >> 4;
  const int b = blockIdx.y >> 4, hh = blockIdx.y & 15;
  const size_t rowb = (size_t)b * T * QKS;
  const int qcol = hh * 64;
  const int kcol = 1024 + hh * 64;
  const size_t vbase = (size_t)hh * 64 * 4096 + (size_t)b * T;

  __shared__ __align__(16) unsigned short p_lds[4][16][40];

#pragma unroll 1
  for (int pass = 0; pass < 2; ++pass) {
    const int qt = (pass == 0) ? (int)blockIdx.x : (31 - (int)blockIdx.x);
    const int qbase = qt * 64 + wave * 16;
    const int trow = qbase + lr;  // this lane's q row (m index)

    U8 qf[2];
#pragma unroll
    for (int j = 0; j < 2; j++)
      qf[j].v = *(const bf16x8*)(qk + rowb + (size_t)trow * QKS + qcol + j * 32 + lg * 8);

    f32x4 oa[4] = {};
    float mrun = -1e30f, lsum = 0.0f;

    const int nsb = (qbase + 15) >> 5;
    for (int sb = 0; sb <= nsb; ++sb) {
      const int s0 = sb * 32;
      f32x4 sa0 = {}, sa1 = {};
#pragma unroll
      for (int j = 0; j < 2; j++) {
        U8 kf0, kf1;
        kf0.v = *(const bf16x8*)(qk + rowb + (size_t)(s0 + lr) * QKS + kcol + j * 32 + lg * 8);
        kf1.v = *(const bf16x8*)(qk + rowb + (size_t)(s0 + 16 + lr) * QKS + kcol + j * 32 + lg * 8);
        sa0 = __builtin_amdgcn_mfma_f32_16x16x32_bf16(kf0.v, qf[j].v, sa0, 0, 0, 0);
        sa1 = __builtin_amdgcn_mfma_f32_16x16x32_bf16(kf1.v, qf[j].v, sa1, 0, 0, 0);
      }
      float sv[8];
#pragma unroll
      for (int r = 0; r < 4; r++) {
        sv[r]     = sa0[r] * 0.125f;
        sv[4 + r] = sa1[r] * 0.125f;
      }
      if (s0 + 31 > qbase) {  // diagonal region: causal mask
#pragma unroll
        for (int r = 0; r < 4; r++) {
          if (s0 + lg * 4 + r > trow)      sv[r]     = -1e30f;
          if (s0 + 16 + lg * 4 + r > trow) sv[4 + r] = -1e30f;
        }
      }
      // lane-local row max over 8, then across the 4 lg-groups
      float tm = sv[0];
#pragma unroll
      for (int i = 1; i < 8; i++) tm = fmaxf(tm, sv[i]);
      tm = fmaxf(tm, __shfl_xor(tm, 16));
      tm = fmaxf(tm, __shfl_xor(tm, 32));
      const float mn = fmaxf(mrun, tm);
      const float corr = __expf(mrun - mn);
      float rs = 0.0f;
#pragma unroll
      for (int i = 0; i < 8; i++) {
        sv[i] = __expf(sv[i] - mn);
        rs += sv[i];
      }
      rs += __shfl_xor(rs, 16);
      rs += __shfl_xor(rs, 32);
      lsum = lsum * corr + rs;
      mrun = mn;
#pragma unroll
      for (int c = 0; c < 4; c++)
#pragma unroll
        for (int r = 0; r < 4; r++) oa[c][r] *= corr;

      // P[m=lr][s] -> LDS (vector writes), re-read as 8-contiguous-s fragment
      ushort4 w0, w1;
      w0.x = f2bf(sv[0]); w0.y = f2bf(sv[1]); w0.z = f2bf(sv[2]); w0.w = f2bf(sv[3]);
      w1.x = f2bf(sv[4]); w1.y = f2bf(sv[5]); w1.z = f2bf(sv[6]); w1.w = f2bf(sv[7]);
      *(ushort4*)&p_lds[wave][lr][lg * 4]      = w0;
      *(ushort4*)&p_lds[wave][lr][16 + lg * 4] = w1;
      asm volatile("" ::: "memory");
      U8 pf;
      pf.v = *(const bf16x8*)&p_lds[wave][lr][lg * 8];
      asm volatile("" ::: "memory");

#pragma unroll
      for (int c = 0; c < 4; c++) {
        U8 vf;
        vf.v = *(const bf16x8*)(vT + vbase + (size_t)(c * 16 + lr) * 4096 + s0 + lg * 8);
        oa[c] = __builtin_amdgcn_mfma_f32_16x16x32_bf16(vf.v, pf.v, oa[c], 0, 0, 0);
      }
    }

    const float inv = 1.0f / lsum;
#pragma unroll
    for (int c = 0; c < 4; c++) {
      ushort4 ov;
      ov.x = f2bf(oa[c][0] * inv);
      ov.y = f2bf(oa[c][1] * inv);
      ov.z = f2bf(oa[c][2] * inv);
      ov.w = f2bf(oa[c][3] * inv);
      *(ushort4*)(o + (size_t)(b * T + trow) * C + hh * 64 + c * 16 + lg * 4) = ov;
    }
  }
}

// ---------------------------------------------------------------------------
// Orchestration
// ---------------------------------------------------------------------------
extern "C" void kernel_launch(void* const* d_in, const int* in_sizes, int n_in,
                              void* d_out, int out_size, void* d_ws, size_t ws_size,
                              hipStream_t stream) {
  (void)in_sizes; (void)n_in; (void)out_size; (void)ws_size;
  const int T = 2048, C = 1024, M = 2 * T, C4 = 4 * C;

  const float* x     = (const float*)d_in[0];
  const float* Wq    = (const float*)d_in[1];
  const float* Wk    = (const float*)d_in[2];
  const float* Wv    = (const float*)d_in[3];
  const float* Wproj = (const float*)d_in[4];
  const float* bproj = (const float*)d_in[5];
  const float* W1    = (const float*)d_in[6];
  const float* b1    = (const float*)d_in[7];
  const float* W2    = (const float*)d_in[8];
  const float* b2    = (const float*)d_in[9];
  const float* ln1g  = (const float*)d_in[10];
  const float* ln1b  = (const float*)d_in[11];
  const float* ln2g  = (const float*)d_in[12];
  const float* ln2b  = (const float*)d_in[13];
  float* out = (float*)d_out;

  char* ws = (char*)d_ws;
  const size_t MBy = (size_t)1 << 20;
  unsigned short* WqkvT = (unsigned short*)(ws + 0 * MBy);  // 6 MB [3072][1024]
  unsigned short* WqT = WqkvT;                              //   rows 0..1023
  unsigned short* WkT = WqkvT + 1024 * 1024;                //   rows 1024..2047
  unsigned short* WvT = WqkvT + 2048 * 1024;                //   rows 2048..3071
  unsigned short* WpT = (unsigned short*)(ws + 6 * MBy);    // 2 MB
  unsigned short* W1T = (unsigned short*)(ws + 8 * MBy);    // 8 MB
  unsigned short* W2T = (unsigned short*)(ws + 16 * MBy);   // 8 MB
  unsigned short* h   = (unsigned short*)(ws + 24 * MBy);   // 8 MB  [4096][1024]
  unsigned short* qkb = (unsigned short*)(ws + 32 * MBy);   // 16 MB [4096][2048]
  unsigned short* vTb = (unsigned short*)(ws + 48 * MBy);   // 8 MB  [1024][4096]
  unsigned short* att = (unsigned short*)(ws + 56 * MBy);   // 8 MB
  float*          x1  = (float*)(ws + 64 * MBy);            // 16 MB
  unsigned short* h2  = att;                                // reuse (att dead after proj)
  unsigned short* ff1 = h;                                  // 32 MB reuse h/qkb/vTb

  const dim3 tb(32, 8);
  transpose_w<<<dim3(2, 32, 16), tb, 0, stream>>>(Wq, WqT, 1024, 64);
  transpose_w<<<dim3(2, 32, 16), tb, 0, stream>>>(Wk, WkT, 1024, 64);
  transpose_w<<<dim3(2, 32, 16), tb, 0, stream>>>(Wv, WvT, 1024, 64);
  transpose_w<<<dim3(32, 32, 1), tb, 0, stream>>>(Wproj, WpT, 1024, 1024);
  transpose_w<<<dim3(128, 32, 1), tb, 0, stream>>>(W1, W1T, 1024, 4096);
  transpose_w<<<dim3(32, 128, 1), tb, 0, stream>>>(W2, W2T, 4096, 1024);

  ln_kernel<<<M, 256, 0, stream>>>(x, ln1g, ln1b, h);

  // Fused QKV: N=3072; cols<2048 -> qkb, cols>=2048 -> vTb (transposed)
  gemm_bt<4><<<dim3(24, 32), 256, 0, stream>>>(h, WqkvT, qkb, vTb, nullptr, nullptr,
                                               M, 3072, C);

  attn_kernel<<<dim3(16, 32), 256, 0, stream>>>(qkb, vTb, att);

  gemm_bt<1><<<dim3(8, 32), 256, 0, stream>>>(att, WpT, x1, nullptr, bproj, x, M, C, C);

  ln_kernel<<<M, 256, 0, stream>>>(x1, ln2g, ln2b, h2);

  gemm_bt<2><<<dim3(32, 32), 256, 0, stream>>>(h2, W1T, ff1, nullptr, b1, nullptr, M, C4, C);
  gemm_bt<3><<<dim3(8, 32), 256, 0, stream>>>(ff1, W2T, out, nullptr, b2, x1, M, C, C4);
}

// Round 3
// 287.856 us; speedup vs baseline: 1.6211x; 1.2107x over previous
//
#include <hip/hip_runtime.h>

// ---------------------------------------------------------------------------
// Types / helpers
// ---------------------------------------------------------------------------
typedef __bf16 bf16x8 __attribute__((ext_vector_type(8)));
typedef float  f32x4  __attribute__((ext_vector_type(4)));

union U8 { bf16x8 v; __bf16 e[8]; unsigned short u[8]; };

__device__ __forceinline__ unsigned short f2bf(float f) {
  unsigned int u = __float_as_uint(f);
  unsigned int r = (u + 0x7FFFu + ((u >> 16) & 1u)) >> 16;  // RNE
  return (unsigned short)r;
}

__device__ __forceinline__ void async16(const void* g, void* l) {
  __builtin_amdgcn_global_load_lds(
      (__attribute__((address_space(1))) void*)(g),
      (__attribute__((address_space(3))) void*)(l), 16, 0, 0);
}

__device__ __forceinline__ void block_barrier() {
  asm volatile("" ::: "memory");
  __builtin_amdgcn_s_barrier();
  asm volatile("" ::: "memory");
}

// ---------------------------------------------------------------------------
// Batched transpose: in fp32 [batch][R][Cc] -> out bf16 [batch*Cc + c][R]
// ---------------------------------------------------------------------------
__global__ __launch_bounds__(256) void transpose_w(
    const float* __restrict__ in, unsigned short* __restrict__ out,
    int R, int Cc) {
  __shared__ float tile[32][33];
  const int batch = blockIdx.z;
  const float* ip = in + (size_t)batch * R * Cc;
  unsigned short* op = out + (size_t)batch * R * Cc;
  const int c0 = blockIdx.x * 32, r0 = blockIdx.y * 32;
  const int tx = threadIdx.x, ty = threadIdx.y;  // 32 x 8
#pragma unroll
  for (int i = 0; i < 32; i += 8)
    tile[ty + i][tx] = ip[(size_t)(r0 + ty + i) * Cc + c0 + tx];
  __syncthreads();
#pragma unroll
  for (int i = 0; i < 32; i += 8)
    op[(size_t)(c0 + ty + i) * R + r0 + tx] = f2bf(tile[tx][ty + i]);
}

// ---------------------------------------------------------------------------
// LayerNorm over rows of 1024, fp32 in -> bf16 out.
// ---------------------------------------------------------------------------
__global__ __launch_bounds__(256) void ln_kernel(
    const float* __restrict__ x, const float* __restrict__ g,
    const float* __restrict__ bta, unsigned short* __restrict__ out) {
  const int C = 1024;
  const int row = blockIdx.x, tid = threadIdx.x;
  const float4 v = ((const float4*)(x + (size_t)row * C))[tid];
  float s  = v.x + v.y + v.z + v.w;
  float ss = v.x * v.x + v.y * v.y + v.z * v.z + v.w * v.w;
#pragma unroll
  for (int off = 32; off > 0; off >>= 1) {
    s  += __shfl_down(s, off);
    ss += __shfl_down(ss, off);
  }
  __shared__ float r0[4], r1[4];
  const int wave = tid >> 6, lane = tid & 63;
  if (lane == 0) { r0[wave] = s; r1[wave] = ss; }
  __syncthreads();
  s  = r0[0] + r0[1] + r0[2] + r0[3];
  ss = r1[0] + r1[1] + r1[2] + r1[3];
  const float mu   = s * (1.0f / C);
  const float var  = ss * (1.0f / C) - mu * mu;
  const float rstd = rsqrtf(var + 1e-5f);
  const float4 gv = ((const float4*)g)[tid];
  const float4 bv = ((const float4*)bta)[tid];
  ushort4 o;
  o.x = f2bf((v.x - mu) * rstd * gv.x + bv.x);
  o.y = f2bf((v.y - mu) * rstd * gv.y + bv.y);
  o.z = f2bf((v.z - mu) * rstd * gv.z + bv.z);
  o.w = f2bf((v.w - mu) * rstd * gv.w + bv.w);
  ((ushort4*)(out + (size_t)row * C))[tid] = o;
}

// ---------------------------------------------------------------------------
// GEMM: C[M][N] = A[M][K] * BT[N][K]^T. bf16 in, fp32 accum. m97 structure.
// EPI: 0 = store bf16 [M][N]
//      1 = +bias+resid -> fp32
//      2 = relu(+bias) -> bf16
//      3 = +bias+resid -> fp32
//      4 = QKV split: col<2048 -> bf16 Cout[M][2048]; col>=2048 ->
//          transposed bf16 Cout2[(col-2048)][M] (ushort4 over 4 rows)
// ---------------------------------------------------------------------------
template <int EPI>
__global__ __launch_bounds__(256, 2) void gemm_bt(
    const unsigned short* __restrict__ A, const unsigned short* __restrict__ BT,
    void* __restrict__ Cout, void* __restrict__ Cout2,
    const float* __restrict__ bias, const float* __restrict__ resid,
    int M, int N, int K) {
  __shared__ __align__(16) unsigned short As[128 * 32];
  __shared__ __align__(16) unsigned short Bs[128 * 32];
  const int tid = threadIdx.x;
  const int lane = tid & 63, wave = tid >> 6;
  const int wrow = wave >> 1, wcol = wave & 1;
  const int lr = lane & 15, lg = lane >> 4;
  const int m0 = blockIdx.y * 128, n0 = blockIdx.x * 128;

  f32x4 acc[4][4] = {};

  const int srow = tid >> 2, k8 = (tid & 3) << 3;
  const size_t arow0 = (size_t)(m0 + srow) * K + k8;
  const size_t brow0 = (size_t)(n0 + srow) * K + k8;
  const size_t skip64 = (size_t)64 * K;

  for (int kt = 0; kt < K; kt += 32) {
    async16(A + arow0 + kt, As + tid * 8);
    async16(A + arow0 + skip64 + kt, As + tid * 8 + 2048);
    async16(BT + brow0 + kt, Bs + tid * 8);
    async16(BT + brow0 + skip64 + kt, Bs + tid * 8 + 2048);
    __syncthreads();
    bf16x8 af[4], bfr[4];
#pragma unroll
    for (int i = 0; i < 4; i++)
      af[i] = *(const bf16x8*)(As + (wrow * 64 + i * 16 + lr) * 32 + lg * 8);
#pragma unroll
    for (int j = 0; j < 4; j++)
      bfr[j] = *(const bf16x8*)(Bs + (wcol * 64 + j * 16 + lr) * 32 + lg * 8);
#pragma unroll
    for (int i = 0; i < 4; i++)
#pragma unroll
      for (int j = 0; j < 4; j++)
        acc[i][j] =
            __builtin_amdgcn_mfma_f32_16x16x32_bf16(af[i], bfr[j], acc[i][j], 0, 0, 0);
    __syncthreads();
  }

#pragma unroll
  for (int j = 0; j < 4; j++) {
    const int col = n0 + wcol * 64 + j * 16 + lr;
    float bv = 0.0f;
    if (EPI == 1 || EPI == 2 || EPI == 3) bv = bias[col];
#pragma unroll
    for (int i = 0; i < 4; i++) {
      const int row0 = m0 + wrow * 64 + i * 16 + lg * 4;
      if (EPI == 4) {
        if (col < 2048) {
#pragma unroll
          for (int r = 0; r < 4; r++)
            ((unsigned short*)Cout)[(size_t)(row0 + r) * 2048 + col] =
                f2bf(acc[i][j][r]);
        } else {
          ushort4 ov;
          ov.x = f2bf(acc[i][j][0]);
          ov.y = f2bf(acc[i][j][1]);
          ov.z = f2bf(acc[i][j][2]);
          ov.w = f2bf(acc[i][j][3]);
          *(ushort4*)((unsigned short*)Cout2 + (size_t)(col - 2048) * 4096 + row0) = ov;
        }
      } else {
#pragma unroll
        for (int r = 0; r < 4; r++) {
          const size_t idx = (size_t)(row0 + r) * N + col;
          const float val = acc[i][j][r];
          if (EPI == 0) {
            ((unsigned short*)Cout)[idx] = f2bf(val);
          } else if (EPI == 1) {
            ((float*)Cout)[idx] = val + bv + resid[idx];
          } else if (EPI == 2) {
            ((unsigned short*)Cout)[idx] = f2bf(fmaxf(val + bv, 0.0f));
          } else {
            ((float*)Cout)[idx] = val + bv + resid[idx];
          }
        }
      }
    }
  }
}

// ---------------------------------------------------------------------------
// Flash attention (causal), swapped-operand, LDS-staged K/V, double-buffered.
// qk: bf16 [B*T][2048] (cols 0..1023 = Q heads, 1024..2047 = K heads)
// vT: bf16 [1024][B*T]  (vT[h*64+d][b*2048+s])
// o : bf16 [B*T][1024]
//
// Block = 4 waves, q-block 64 (16 q-rows/wave), s-blocks of 64, K/V tiles
// staged to LDS via global_load_lds with XOR-swizzled GLOBAL source
// (linear LDS dest; reads apply the same swizzle -> 2-way conflicts only).
// Counted vmcnt(4) + raw s_barrier keeps next tile's 4 loads in flight
// across compute. Defer-max (THR=8) skips O-rescale on most iterations.
// Causal balance: block bx does q-tiles {bx, 31-bx} (33 iters total).
// ---------------------------------------------------------------------------
__global__ __launch_bounds__(256) void attn_kernel(
    const unsigned short* __restrict__ qk, const unsigned short* __restrict__ vT,
    unsigned short* __restrict__ o) {
  const int T = 2048, C = 1024, QKS = 2048;
  const int tid = threadIdx.x;
  const int wave = tid >> 6, lane = tid & 63;
  const int lr = lane & 15, lg = lane >> 4;
  const int b = blockIdx.y >> 4, hh = blockIdx.y & 15;
  const size_t rowb = (size_t)b * T * QKS;
  const int qcol = hh * 64;
  const int kcol = 1024 + hh * 64;
  const int vrow0 = hh * 64;
  const size_t bT = (size_t)b * T;
  const int swe = (lr & 7) << 3;  // element-space XOR swizzle for frag reads

  __shared__ __align__(16) unsigned short Ks[2][64 * 64];
  __shared__ __align__(16) unsigned short Vs[2][64 * 64];
  __shared__ __align__(16) unsigned short Ps[4][16][72];

  // staging geometry: thread t covers rows {t>>3, 32+(t>>3)}, 16B each,
  // global column pre-swizzled so linear LDS ends up XOR-swizzled.
  const int rw = tid >> 3;
  const int c8 = ((tid & 7) ^ (rw & 7)) << 3;

#pragma unroll 1
  for (int pass = 0; pass < 2; ++pass) {
    const int qt = (pass == 0) ? (int)blockIdx.x : (31 - (int)blockIdx.x);
    const int qbase = qt * 64 + wave * 16;
    const int trow = qbase + lr;  // this lane's q row

    U8 qf[2];
#pragma unroll
    for (int j = 0; j < 2; j++)
      qf[j].v = *(const bf16x8*)(qk + rowb + (size_t)trow * QKS + qcol + j * 32 + lg * 8);
    asm volatile("s_waitcnt vmcnt(0)" ::: "memory");

    // prologue: stage s-block 0 into buffer 0
    async16(qk + rowb + (size_t)rw * QKS + kcol + c8, Ks[0] + tid * 8);
    async16(qk + rowb + (size_t)(32 + rw) * QKS + kcol + c8, Ks[0] + 2048 + tid * 8);
    async16(vT + (size_t)(vrow0 + rw) * 4096 + bT + c8, Vs[0] + tid * 8);
    async16(vT + (size_t)(vrow0 + 32 + rw) * 4096 + bT + c8, Vs[0] + 2048 + tid * 8);

    f32x4 oa[4] = {};
    float mrun = -1e30f, lsum = 0.0f;
    int cur = 0;

    for (int sb = 0; sb <= qt; ++sb) {
      if (sb < qt) {  // stage next s-block into the other buffer
        const int s1 = (sb + 1) * 64;
        const int nb = cur ^ 1;
        async16(qk + rowb + (size_t)(s1 + rw) * QKS + kcol + c8, Ks[nb] + tid * 8);
        async16(qk + rowb + (size_t)(s1 + 32 + rw) * QKS + kcol + c8, Ks[nb] + 2048 + tid * 8);
        async16(vT + (size_t)(vrow0 + rw) * 4096 + bT + s1 + c8, Vs[nb] + tid * 8);
        async16(vT + (size_t)(vrow0 + 32 + rw) * 4096 + bT + s1 + c8, Vs[nb] + 2048 + tid * 8);
        asm volatile("s_waitcnt vmcnt(4)" ::: "memory");
      } else {
        asm volatile("s_waitcnt vmcnt(0)" ::: "memory");
      }
      block_barrier();  // all waves' loads for tile sb complete

      const unsigned short* Kc = Ks[cur];
      const unsigned short* Vc = Vs[cur];
      const int s0 = sb * 64;

      // --- QK^T: S^T frags, lane (lr,lg) -> q=qbase+lr, s=s0+mf*16+lg*4+r
      f32x4 sa[4] = {};
#pragma unroll
      for (int j = 0; j < 2; j++) {
#pragma unroll
        for (int mf = 0; mf < 4; mf++) {
          U8 kf;
          kf.v = *(const bf16x8*)(Kc + (mf * 16 + lr) * 64 + ((j * 32 + lg * 8) ^ swe));
          sa[mf] = __builtin_amdgcn_mfma_f32_16x16x32_bf16(kf.v, qf[j].v, sa[mf], 0, 0, 0);
        }
      }
      float sv[16];
#pragma unroll
      for (int mf = 0; mf < 4; mf++)
#pragma unroll
        for (int r = 0; r < 4; r++) sv[mf * 4 + r] = sa[mf][r] * 0.125f;

      if (sb == qt) {  // diagonal block: causal mask
#pragma unroll
        for (int mf = 0; mf < 4; mf++)
#pragma unroll
          for (int r = 0; r < 4; r++)
            if (s0 + mf * 16 + lg * 4 + r > trow) sv[mf * 4 + r] = -1e30f;
      }

      float tm = sv[0];
#pragma unroll
      for (int i = 1; i < 16; i++) tm = fmaxf(tm, sv[i]);
      tm = fmaxf(tm, __shfl_xor(tm, 16));
      tm = fmaxf(tm, __shfl_xor(tm, 32));

      if (!__all(tm <= mrun + 8.0f)) {  // defer-max: rescale only when needed
        const float mn = fmaxf(mrun, tm);
        const float corr = __expf(mrun - mn);
        lsum *= corr;
#pragma unroll
        for (int c = 0; c < 4; c++)
#pragma unroll
          for (int r = 0; r < 4; r++) oa[c][r] *= corr;
        mrun = mn;
      }

      float rs = 0.0f;
#pragma unroll
      for (int i = 0; i < 16; i++) {
        sv[i] = __expf(sv[i] - mrun);
        rs += sv[i];
      }
      rs += __shfl_xor(rs, 16);
      rs += __shfl_xor(rs, 32);
      lsum += rs;

      // P -> LDS [q=lr][s], re-read as PV B-frags (8 consecutive s per lane)
#pragma unroll
      for (int mf = 0; mf < 4; mf++) {
        ushort4 w;
        w.x = f2bf(sv[mf * 4 + 0]);
        w.y = f2bf(sv[mf * 4 + 1]);
        w.z = f2bf(sv[mf * 4 + 2]);
        w.w = f2bf(sv[mf * 4 + 3]);
        *(ushort4*)&Ps[wave][lr][mf * 16 + lg * 4] = w;
      }
      asm volatile("" ::: "memory");
      U8 pb[2];
      pb[0].v = *(const bf16x8*)&Ps[wave][lr][lg * 8];
      pb[1].v = *(const bf16x8*)&Ps[wave][lr][32 + lg * 8];
      asm volatile("" ::: "memory");

      // --- PV: O^T frags, lane (lr,lg) -> q=qbase+lr, d=c*16+lg*4+r
#pragma unroll
      for (int c = 0; c < 4; c++) {
#pragma unroll
        for (int ks = 0; ks < 2; ks++) {
          U8 vf;
          vf.v = *(const bf16x8*)(Vc + (c * 16 + lr) * 64 + ((ks * 32 + lg * 8) ^ swe));
          oa[c] = __builtin_amdgcn_mfma_f32_16x16x32_bf16(vf.v, pb[ks].v, oa[c], 0, 0, 0);
        }
      }

      block_barrier();  // compute on buf[cur] done; safe to overwrite next iter
      cur ^= 1;
    }

    const float inv = 1.0f / lsum;
#pragma unroll
    for (int c = 0; c < 4; c++) {
      ushort4 ov;
      ov.x = f2bf(oa[c][0] * inv);
      ov.y = f2bf(oa[c][1] * inv);
      ov.z = f2bf(oa[c][2] * inv);
      ov.w = f2bf(oa[c][3] * inv);
      *(ushort4*)(o + (size_t)(bT + trow) * C + hh * 64 + c * 16 + lg * 4) = ov;
    }
  }
}

// ---------------------------------------------------------------------------
// Orchestration
// ---------------------------------------------------------------------------
extern "C" void kernel_launch(void* const* d_in, const int* in_sizes, int n_in,
                              void* d_out, int out_size, void* d_ws, size_t ws_size,
                              hipStream_t stream) {
  (void)in_sizes; (void)n_in; (void)out_size; (void)ws_size;
  const int T = 2048, C = 1024, M = 2 * T, C4 = 4 * C;

  const float* x     = (const float*)d_in[0];
  const float* Wq    = (const float*)d_in[1];
  const float* Wk    = (const float*)d_in[2];
  const float* Wv    = (const float*)d_in[3];
  const float* Wproj = (const float*)d_in[4];
  const float* bproj = (const float*)d_in[5];
  const float* W1    = (const float*)d_in[6];
  const float* b1    = (const float*)d_in[7];
  const float* W2    = (const float*)d_in[8];
  const float* b2    = (const float*)d_in[9];
  const float* ln1g  = (const float*)d_in[10];
  const float* ln1b  = (const float*)d_in[11];
  const float* ln2g  = (const float*)d_in[12];
  const float* ln2b  = (const float*)d_in[13];
  float* out = (float*)d_out;

  char* ws = (char*)d_ws;
  const size_t MBy = (size_t)1 << 20;
  unsigned short* WqkvT = (unsigned short*)(ws + 0 * MBy);  // 6 MB [3072][1024]
  unsigned short* WqT = WqkvT;
  unsigned short* WkT = WqkvT + 1024 * 1024;
  unsigned short* WvT = WqkvT + 2048 * 1024;
  unsigned short* WpT = (unsigned short*)(ws + 6 * MBy);    // 2 MB
  unsigned short* W1T = (unsigned short*)(ws + 8 * MBy);    // 8 MB
  unsigned short* W2T = (unsigned short*)(ws + 16 * MBy);   // 8 MB
  unsigned short* h   = (unsigned short*)(ws + 24 * MBy);   // 8 MB  [4096][1024]
  unsigned short* qkb = (unsigned short*)(ws + 32 * MBy);   // 16 MB [4096][2048]
  unsigned short* vTb = (unsigned short*)(ws + 48 * MBy);   // 8 MB  [1024][4096]
  unsigned short* att = (unsigned short*)(ws + 56 * MBy);   // 8 MB
  float*          x1  = (float*)(ws + 64 * MBy);            // 16 MB
  unsigned short* h2  = att;                                // reuse
  unsigned short* ff1 = h;                                  // reuse h/qkb/vTb

  const dim3 tb(32, 8);
  transpose_w<<<dim3(2, 32, 16), tb, 0, stream>>>(Wq, WqT, 1024, 64);
  transpose_w<<<dim3(2, 32, 16), tb, 0, stream>>>(Wk, WkT, 1024, 64);
  transpose_w<<<dim3(2, 32, 16), tb, 0, stream>>>(Wv, WvT, 1024, 64);
  transpose_w<<<dim3(32, 32, 1), tb, 0, stream>>>(Wproj, WpT, 1024, 1024);
  transpose_w<<<dim3(128, 32, 1), tb, 0, stream>>>(W1, W1T, 1024, 4096);
  transpose_w<<<dim3(32, 128, 1), tb, 0, stream>>>(W2, W2T, 4096, 1024);

  ln_kernel<<<M, 256, 0, stream>>>(x, ln1g, ln1b, h);

  gemm_bt<4><<<dim3(24, 32), 256, 0, stream>>>(h, WqkvT, qkb, vTb, nullptr, nullptr,
                                               M, 3072, C);

  attn_kernel<<<dim3(16, 32), 256, 0, stream>>>(qkb, vTb, att);

  gemm_bt<1><<<dim3(8, 32), 256, 0, stream>>>(att, WpT, x1, nullptr, bproj, x, M, C, C);

  ln_kernel<<<M, 256, 0, stream>>>(x1, ln2g, ln2b, h2);

  gemm_bt<2><<<dim3(32, 32), 256, 0, stream>>>(h2, W1T, ff1, nullptr, b1, nullptr, M, C4, C);
  gemm_bt<3><<<dim3(8, 32), 256, 0, stream>>>(ff1, W2T, out, nullptr, b2, x1, M, C, C4);
}